// Round 9
// baseline (342.131 us; speedup 1.0000x reference)
//
#include <hip/hip_runtime.h>
#include <hip/hip_bf16.h>
#include <stdint.h>

// Problem dims
#define NB 256
#define NL 196
#define NE 2048
#define ND 512
#define NA 512
#define NM (NB * NL)  // 50176

#define BPCOPY (1u << 20)  // elems per replicated B copy (2 MB); 8 copies, one per XCD

typedef __attribute__((ext_vector_type(4))) float f32x4;
typedef __attribute__((ext_vector_type(8))) short bf16x8;

static __device__ __forceinline__ unsigned short f2bf(float f) {
  __hip_bfloat16 h = __float2bfloat16(f);
  unsigned short u;
  __builtin_memcpy(&u, &h, 2);
  return u;
}

// ---------------- kernel 0: prep
// blocks 0..255:  pack W_enc into B-fragment order bf16, replicated 8x (one per XCD)
// blocks 256..287: decoder GEMV, 8 batches per block
__global__ __launch_bounds__(512) void k_prep(
    const float* __restrict__ W, unsigned short* __restrict__ Bp,
    const float* __restrict__ dec, const float* __restrict__ Wd,
    const float* __restrict__ bd, const float* __restrict__ be,
    float* __restrict__ d2) {
  if (blockIdx.x < 256) {
    int t = blockIdx.x * 512 + threadIdx.x;  // 0..131071
    int lane = t & 63;
    int kt32 = (t >> 6) & 63;
    int ntile = t >> 12;  // 0..31
    int col = ntile * 16 + (lane & 15);
    int k0 = kt32 * 32 + ((lane >> 4) << 3);
    bf16x8 o;
#pragma unroll
    for (int j = 0; j < 8; ++j) o[j] = (short)f2bf(W[(size_t)(k0 + j) * NA + col]);
#pragma unroll
    for (int x = 0; x < 8; ++x)
      *reinterpret_cast<bf16x8*>(Bp + (size_t)x * BPCOPY + ((size_t)t << 3)) = o;
  } else {
    __shared__ float dh[8][ND];
    const int b0 = (blockIdx.x - 256) * 8, tid = threadIdx.x;
#pragma unroll
    for (int j = 0; j < 8; ++j) dh[j][tid] = dec[(size_t)(b0 + j) * ND + tid];
    __syncthreads();
    float base = bd[tid] + be[tid];
    float acc[8];
#pragma unroll
    for (int j = 0; j < 8; ++j) acc[j] = base;
#pragma unroll 4
    for (int e = 0; e < ND; ++e) {
      float w = Wd[(size_t)e * NA + tid];
#pragma unroll
      for (int j = 0; j < 8; ++j) acc[j] = fmaf(dh[j][e], w, acc[j]);
    }
#pragma unroll
    for (int j = 0; j < 8; ++j) d2[(size_t)(b0 + j) * NA + tid] = acc[j];
  }
}

// ---------------- kernel 1: main fused GEMM + relu-dot epilogue
// 4-wave (256-thread) blocks, tile 64 rows x 256 cols (col-split 2).
// 4 blocks/CU = 4 independent barrier domains (m97/m114: implicit wave-level
// pipelining needs >=3 domains). att written as 2 col-half partials.
#define BM 64
#define BK 64
#define KT (NE / BK)  // 32

__global__ __launch_bounds__(256, 4) void k_main(
    const float* __restrict__ A,            // [NM][NE] fp32
    const unsigned short* __restrict__ Bp,  // packed bf16 B, 8 replicas
    const float* __restrict__ d2,           // [NB][NA]
    const float* __restrict__ Watt,         // [NA]
    float* __restrict__ att_part)           // [2][NM] (col-half partial dots)
{
  __shared__ unsigned short As[2][BM * BK];  // 2 x 8 KB, XOR-swizzled chunks
  __shared__ float att_w[4][BM];

  const int tid = threadIdx.x;
  const int lane = tid & 63;
  const int wid = tid >> 6;     // 0..3 -> col slice wid*64 within this block's half
  const int lq = lane >> 4;     // 0..3
  const int lr = lane & 15;
  const int wgid = blockIdx.x;
  const int ch = wgid & 1;          // col half 0/1 (fastest-varying: pair shares A tile)
  const int rowt = wgid >> 1;       // row tile 0..783
  const int row0 = rowt * BM;
  const int col0 = ch * 256 + wid * 64;

  // acc init with d2 (folds decoder term + b_dec + b_enc into MFMA C-in)
  f32x4 acc[4][4];
#pragma unroll
  for (int mf = 0; mf < 4; ++mf)
#pragma unroll
    for (int r = 0; r < 4; ++r) {
      int rowg = row0 + mf * 16 + lq * 4 + r;
      int bb = rowg / NL;
      const float* d2r = d2 + (size_t)bb * NA + col0 + lr;
#pragma unroll
      for (int nf = 0; nf < 4; ++nf) acc[mf][nf][r] = d2r[nf * 16];
    }

  // A staging: thread -> row = tid>>2 (0..63), 16 consecutive floats at (tid&3)*16
  const int srow = tid >> 2;
  const int scb = (tid & 3) * 2;  // chunk (8 bf16) index; 8 chunks per row
  const float* ag = A + (size_t)(row0 + srow) * NE + scb * 8;
  const int wo0 = srow * BK + ((scb ^ (srow & 7)) << 3);
  const int wo1 = srow * BK + (((scb + 1) ^ (srow & 7)) << 3);

  f32x4 s0, s1, s2, s3;
  auto cvt_store = [&](int buf) {
    bf16x8 o0, o1;
#pragma unroll
    for (int j = 0; j < 4; ++j) {
      o0[j] = (short)f2bf(s0[j]); o0[j + 4] = (short)f2bf(s1[j]);
      o1[j] = (short)f2bf(s2[j]); o1[j + 4] = (short)f2bf(s3[j]);
    }
    *reinterpret_cast<bf16x8*>(&As[buf][wo0]) = o0;
    *reinterpret_cast<bf16x8*>(&As[buf][wo1]) = o1;
  };

  // prologue: stage kt=0
  s0 = *reinterpret_cast<const f32x4*>(ag);
  s1 = *reinterpret_cast<const f32x4*>(ag + 4);
  s2 = *reinterpret_cast<const f32x4*>(ag + 8);
  s3 = *reinterpret_cast<const f32x4*>(ag + 12);
  cvt_store(0);
  __syncthreads();

  // per-wave B base in this XCD's replica (wgid%8 matches round-robin dispatch):
  // Bp[ntile(32)][kt32(64)][lane(64)][8]; this wave's ntiles = ch*16 + wid*4 ..+3
  const unsigned short* bpw = Bp + (size_t)(wgid & 7) * BPCOPY
                                 + (size_t)(ch * 16 + wid * 4) * 32768 + lane * 8;

  for (int kt = 0; kt < KT; ++kt) {
    const int cur = kt & 1;
    // B loads (local-XCD L2)
    bf16x8 bf[2][4];
#pragma unroll
    for (int ks = 0; ks < 2; ++ks)
#pragma unroll
      for (int nf = 0; nf < 4; ++nf)
        bf[ks][nf] = *reinterpret_cast<const bf16x8*>(bpw + (size_t)nf * 32768 + (size_t)(kt * 2 + ks) * 512);
    // A prefetch for kt+1
    if (kt + 1 < KT) {
      const float* agn = ag + (size_t)(kt + 1) * BK;
      s0 = *reinterpret_cast<const f32x4*>(agn);
      s1 = *reinterpret_cast<const f32x4*>(agn + 4);
      s2 = *reinterpret_cast<const f32x4*>(agn + 8);
      s3 = *reinterpret_cast<const f32x4*>(agn + 12);
    }
    // MFMA section: 32 MFMAs/wave/kt
#pragma unroll
    for (int ks = 0; ks < 2; ++ks)
#pragma unroll
      for (int mf = 0; mf < 4; ++mf) {
        const int rrow = mf * 16 + lr;
        const int chunk = (ks * 4 + lq) ^ (lr & 7);
        bf16x8 af = *reinterpret_cast<const bf16x8*>(&As[cur][rrow * BK + (chunk << 3)]);
#pragma unroll
        for (int nf = 0; nf < 4; ++nf)
          acc[mf][nf] = __builtin_amdgcn_mfma_f32_16x16x32_bf16(af, bf[ks][nf], acc[mf][nf], 0, 0, 0);
      }
    // write staged A for kt+1
    if (kt + 1 < KT) cvt_store(cur ^ 1);
    __syncthreads();
  }

  // epilogue: relu, dot with this wave's W_att slice, 16-lane reduce
  float w[4];
#pragma unroll
  for (int nf = 0; nf < 4; ++nf) w[nf] = Watt[col0 + nf * 16 + lr];
#pragma unroll
  for (int mf = 0; mf < 4; ++mf)
#pragma unroll
    for (int r = 0; r < 4; ++r) {
      float s = 0.f;
#pragma unroll
      for (int nf = 0; nf < 4; ++nf) s = fmaf(fmaxf(acc[mf][nf][r], 0.f), w[nf], s);
      s += __shfl_xor(s, 1);
      s += __shfl_xor(s, 2);
      s += __shfl_xor(s, 4);
      s += __shfl_xor(s, 8);
      if (lr == 0) att_w[wid][mf * 16 + lq * 4 + r] = s;
    }
  __syncthreads();
  if (tid < BM) {
    float s = att_w[0][tid] + att_w[1][tid] + att_w[2][tid] + att_w[3][tid];
    att_part[(size_t)ch * NM + row0 + tid] = s;
  }
}

// ---------------- kernel 2: fused softmax + weighted sum
// b_att dropped: softmax is shift-invariant, so it affects neither alpha nor awe.
__global__ __launch_bounds__(512) void k_awe(
    const float* __restrict__ enc, const float* __restrict__ att_part,
    float* __restrict__ alpha_out, float* __restrict__ awe) {
  __shared__ float al[256];
  const int b = blockIdx.x, tid = threadIdx.x;

  if (tid < 64) {  // wave 0: softmax over L=196 (sum the two col-half partials)
    const int lane = tid;
    const float* a0 = att_part + (size_t)b * NL;
    const float* a1 = att_part + (size_t)NM + (size_t)b * NL;
    float v[4];
#pragma unroll
    for (int i = 0; i < 4; ++i) {
      int l = i * 64 + lane;
      v[i] = (l < NL) ? (a0[l] + a1[l]) : -1e30f;
    }
    float m = fmaxf(fmaxf(v[0], v[1]), fmaxf(v[2], v[3]));
#pragma unroll
    for (int o = 32; o >= 1; o >>= 1) m = fmaxf(m, __shfl_xor(m, o));
    float e[4];
    float s = 0.f;
#pragma unroll
    for (int i = 0; i < 4; ++i) {
      int l = i * 64 + lane;
      e[i] = (l < NL) ? __expf(v[i] - m) : 0.f;
      s += e[i];
    }
#pragma unroll
    for (int o = 32; o >= 1; o >>= 1) s += __shfl_xor(s, o);
    float inv = 1.f / s;
#pragma unroll
    for (int i = 0; i < 4; ++i) {
      int l = i * 64 + lane;
      if (l < NL) {
        float a = e[i] * inv;
        al[l] = a;
        alpha_out[(size_t)b * NL + l] = a;
      }
    }
  }
  __syncthreads();

  // weighted sum: each thread owns 4 consecutive e; 4 independent accumulator sets
  const float* ep = enc + (size_t)b * NL * NE + tid * 4;
  f32x4 a0 = {0.f, 0.f, 0.f, 0.f}, a1 = a0, a2 = a0, a3 = a0;
#pragma unroll 2
  for (int l = 0; l < NL; l += 4) {  // NL = 196 = 4*49
    f32x4 v0 = *reinterpret_cast<const f32x4*>(ep + (size_t)l * NE);
    f32x4 v1 = *reinterpret_cast<const f32x4*>(ep + (size_t)(l + 1) * NE);
    f32x4 v2 = *reinterpret_cast<const f32x4*>(ep + (size_t)(l + 2) * NE);
    f32x4 v3 = *reinterpret_cast<const f32x4*>(ep + (size_t)(l + 3) * NE);
    float c0 = al[l], c1 = al[l + 1], c2 = al[l + 2], c3 = al[l + 3];
#pragma unroll
    for (int j = 0; j < 4; ++j) {
      a0[j] = fmaf(c0, v0[j], a0[j]);
      a1[j] = fmaf(c1, v1[j], a1[j]);
      a2[j] = fmaf(c2, v2[j], a2[j]);
      a3[j] = fmaf(c3, v3[j], a3[j]);
    }
  }
  f32x4 s4;
#pragma unroll
  for (int j = 0; j < 4; ++j) s4[j] = (a0[j] + a1[j]) + (a2[j] + a3[j]);
  *reinterpret_cast<f32x4*>(awe + (size_t)b * NE + tid * 4) = s4;
}

extern "C" void kernel_launch(void* const* d_in, const int* in_sizes, int n_in,
                              void* d_out, int out_size, void* d_ws, size_t ws_size,
                              hipStream_t stream) {
  const float* enc  = (const float*)d_in[0];
  const float* dec  = (const float*)d_in[1];
  const float* Wenc = (const float*)d_in[2];
  const float* benc = (const float*)d_in[3];
  const float* Wdec = (const float*)d_in[4];
  const float* bdec = (const float*)d_in[5];
  const float* Watt = (const float*)d_in[6];

  float* awe   = (float*)d_out;                     // [NB][NE]
  float* alpha = (float*)d_out + (size_t)NB * NE;   // [NB][NL]

  char* ws = (char*)d_ws;
  unsigned short* Bp = (unsigned short*)ws;                        // 16 MB (8 replicas)
  float* d2  = (float*)(ws + (size_t)16 * 1024 * 1024);            // 512 KB
  float* att = (float*)(ws + (size_t)16 * 1024 * 1024 + 512 * 1024);  // 2 x 200 KB partials

  k_prep<<<dim3(288), dim3(512), 0, stream>>>(Wenc, Bp, dec, Wdec, bdec, benc, d2);
  k_main<<<dim3((NM / BM) * 2), dim3(256), 0, stream>>>(enc, Bp, d2, Watt, att);
  k_awe<<<dim3(NB), dim3(512), 0, stream>>>(enc, att, alpha, awe);
}

// Round 10
// 266.065 us; speedup vs baseline: 1.2859x; 1.2859x over previous
//
#include <hip/hip_runtime.h>
#include <hip/hip_bf16.h>
#include <stdint.h>

// Problem dims
#define NB 256
#define NL 196
#define NE 2048
#define ND 512
#define NA 512
#define NM (NB * NL)  // 50176

typedef __attribute__((ext_vector_type(4))) float f32x4;
typedef __attribute__((ext_vector_type(8))) short bf16x8;

static __device__ __forceinline__ unsigned short f2bf(float f) {
  __hip_bfloat16 h = __float2bfloat16(f);
  unsigned short u;
  __builtin_memcpy(&u, &h, 2);
  return u;
}

// Non-temporal f32x4 load: nt flag -> A stream does not evict B from per-XCD L2.
static __device__ __forceinline__ f32x4 ntload4(const float* p) {
  return __builtin_nontemporal_load(reinterpret_cast<const f32x4*>(p));
}

// ---------------- kernel 0: prep
// blocks 0..255:  pack W_enc into B-fragment order bf16 (single copy; read-only data
//                 caches independently in each XCD's L2 once A stops evicting it)
// blocks 256..287: decoder GEMV, 8 batches per block
__global__ __launch_bounds__(512) void k_prep(
    const float* __restrict__ W, unsigned short* __restrict__ Bp,
    const float* __restrict__ dec, const float* __restrict__ Wd,
    const float* __restrict__ bd, const float* __restrict__ be,
    float* __restrict__ d2) {
  if (blockIdx.x < 256) {
    int t = blockIdx.x * 512 + threadIdx.x;  // 0..131071
    int lane = t & 63;
    int kt32 = (t >> 6) & 63;
    int ntile = t >> 12;  // 0..31
    int col = ntile * 16 + (lane & 15);
    int k0 = kt32 * 32 + ((lane >> 4) << 3);
    bf16x8 o;
#pragma unroll
    for (int j = 0; j < 8; ++j) o[j] = (short)f2bf(W[(size_t)(k0 + j) * NA + col]);
    *reinterpret_cast<bf16x8*>(Bp + ((size_t)t << 3)) = o;
  } else {
    __shared__ float dh[8][ND];
    const int b0 = (blockIdx.x - 256) * 8, tid = threadIdx.x;
#pragma unroll
    for (int j = 0; j < 8; ++j) dh[j][tid] = dec[(size_t)(b0 + j) * ND + tid];
    __syncthreads();
    float base = bd[tid] + be[tid];
    float acc[8];
#pragma unroll
    for (int j = 0; j < 8; ++j) acc[j] = base;
#pragma unroll 4
    for (int e = 0; e < ND; ++e) {
      float w = Wd[(size_t)e * NA + tid];
#pragma unroll
      for (int j = 0; j < 8; ++j) acc[j] = fmaf(dh[j][e], w, acc[j]);
    }
#pragma unroll
    for (int j = 0; j < 8; ++j) d2[(size_t)(b0 + j) * NA + tid] = acc[j];
  }
}

// ---------------- kernel 1: main fused GEMM + relu-dot epilogue
// att[row] = sum_a relu( (enc@W_enc)[row][a] + d2[b(row)][a] ) * W_att[a] + b_att
#define BM 64
#define BK 64
#define KT (NE / BK)  // 32

__global__ __launch_bounds__(512, 4) void k_main(
    const float* __restrict__ A,            // [NM][NE] fp32
    const unsigned short* __restrict__ Bp,  // packed bf16 B
    const float* __restrict__ d2,           // [NB][NA]
    const float* __restrict__ Watt,         // [NA]
    const float* __restrict__ batt,         // [1]
    float* __restrict__ att)                // [NM]
{
  __shared__ unsigned short As[2][BM * BK];  // 8 KB each, XOR-swizzled rows
  __shared__ float att_w[8][BM];

  const int tid = threadIdx.x;
  const int lane = tid & 63;
  const int wid = tid >> 6;   // wave 0..7 -> col slice wid*64
  const int lq = lane >> 4;   // 0..3
  const int lr = lane & 15;
  const int row0 = blockIdx.x * BM;

  // acc init with d2 (folds decoder term + both biases into MFMA C-in)
  f32x4 acc[4][4];
#pragma unroll
  for (int mf = 0; mf < 4; ++mf)
#pragma unroll
    for (int r = 0; r < 4; ++r) {
      int rowg = row0 + mf * 16 + lq * 4 + r;
      int bb = rowg / NL;
      const float* d2r = d2 + (size_t)bb * NA + wid * 64 + lr;
#pragma unroll
      for (int nf = 0; nf < 4; ++nf) acc[mf][nf][r] = d2r[nf * 16];
    }

  // A staging map: thread -> (row 0..63, 8-elem k-chunk 0..7)
  const int srow = tid >> 3;
  const int skc = tid & 7;
  const float* ag = A + (size_t)(row0 + srow) * NE + skc * 8;
  const int swz_w = srow * 64 + ((skc ^ (srow & 7)) << 3);  // ushort index, 16B-swizzled

  f32x4 s0, s1;
  auto cvt_store = [&](int buf) {
    bf16x8 o;
    o[0] = (short)f2bf(s0[0]); o[1] = (short)f2bf(s0[1]);
    o[2] = (short)f2bf(s0[2]); o[3] = (short)f2bf(s0[3]);
    o[4] = (short)f2bf(s1[0]); o[5] = (short)f2bf(s1[1]);
    o[6] = (short)f2bf(s1[2]); o[7] = (short)f2bf(s1[3]);
    *reinterpret_cast<bf16x8*>(&As[buf][swz_w]) = o;
  };

  // prologue: stage kt=0 (non-temporal A)
  s0 = ntload4(ag);
  s1 = ntload4(ag + 4);
  cvt_store(0);
  __syncthreads();

  // per-wave B base: Bp[ntile(32)][kt32(64)][lane(64)][8], ntile = wid*4+nf
  const unsigned short* bpw = Bp + (size_t)(wid * 4) * 32768 + lane * 8;

  for (int kt = 0; kt < KT; ++kt) {
    const int cur = kt & 1;
    // B-fragment loads (normal loads -> L2-resident now that A is nt)
    bf16x8 bf[2][4];
#pragma unroll
    for (int ks = 0; ks < 2; ++ks)
#pragma unroll
      for (int nf = 0; nf < 4; ++nf)
        bf[ks][nf] = *reinterpret_cast<const bf16x8*>(bpw + (size_t)nf * 32768 + (size_t)(kt * 2 + ks) * 512);
    // A prefetch for kt+1 (non-temporal; drains at cvt_store after the MFMA section)
    if (kt + 1 < KT) {
      const float* agn = ag + (size_t)(kt + 1) * BK;
      s0 = ntload4(agn);
      s1 = ntload4(agn + 4);
    }
    // MFMA section
#pragma unroll
    for (int ks = 0; ks < 2; ++ks)
#pragma unroll
      for (int mf = 0; mf < 4; ++mf) {
        const int rrow = mf * 16 + lr;
        const int chunk = (ks * 4 + lq) ^ (lr & 7);
        bf16x8 af = *reinterpret_cast<const bf16x8*>(&As[cur][rrow * 64 + (chunk << 3)]);
#pragma unroll
        for (int nf = 0; nf < 4; ++nf)
          acc[mf][nf] = __builtin_amdgcn_mfma_f32_16x16x32_bf16(af, bf[ks][nf], acc[mf][nf], 0, 0, 0);
      }
    // write staged A for kt+1
    if (kt + 1 < KT) cvt_store(cur ^ 1);
    __syncthreads();
  }

  // epilogue: relu, dot with W_att slice, reduce 16 lanes -> row partial
  float w[4];
#pragma unroll
  for (int nf = 0; nf < 4; ++nf) w[nf] = Watt[wid * 64 + nf * 16 + lr];
#pragma unroll
  for (int mf = 0; mf < 4; ++mf)
#pragma unroll
    for (int r = 0; r < 4; ++r) {
      float s = 0.f;
#pragma unroll
      for (int nf = 0; nf < 4; ++nf) s = fmaf(fmaxf(acc[mf][nf][r], 0.f), w[nf], s);
      s += __shfl_xor(s, 1);
      s += __shfl_xor(s, 2);
      s += __shfl_xor(s, 4);
      s += __shfl_xor(s, 8);
      if (lr == 0) att_w[wid][mf * 16 + lq * 4 + r] = s;
    }
  __syncthreads();
  if (tid < BM) {
    float s = 0.f;
#pragma unroll
    for (int wv = 0; wv < 8; ++wv) s += att_w[wv][tid];
    att[row0 + tid] = s + batt[0];
  }
}

// ---------------- kernel 2: fused softmax + weighted sum
// 2 blocks per batch (e-split); softmax computed redundantly in both.
__global__ __launch_bounds__(256) void k_awe(
    const float* __restrict__ enc, const float* __restrict__ att,
    float* __restrict__ alpha_out, float* __restrict__ awe) {
  __shared__ float al[256];
  const int b = blockIdx.x >> 1, ch = blockIdx.x & 1, tid = threadIdx.x;

  if (tid < 64) {  // wave 0: softmax over L=196
    const int lane = tid;
    const float* ar = att + (size_t)b * NL;
    float v[4];
#pragma unroll
    for (int i = 0; i < 4; ++i) {
      int l = i * 64 + lane;
      v[i] = (l < NL) ? ar[l] : -1e30f;
    }
    float m = fmaxf(fmaxf(v[0], v[1]), fmaxf(v[2], v[3]));
#pragma unroll
    for (int o = 32; o >= 1; o >>= 1) m = fmaxf(m, __shfl_xor(m, o));
    float e[4];
    float s = 0.f;
#pragma unroll
    for (int i = 0; i < 4; ++i) {
      int l = i * 64 + lane;
      e[i] = (l < NL) ? __expf(v[i] - m) : 0.f;
      s += e[i];
    }
#pragma unroll
    for (int o = 32; o >= 1; o >>= 1) s += __shfl_xor(s, o);
    float inv = 1.f / s;
#pragma unroll
    for (int i = 0; i < 4; ++i) {
      int l = i * 64 + lane;
      if (l < NL) {
        float a = e[i] * inv;
        al[l] = a;
        if (ch == 0) alpha_out[(size_t)b * NL + l] = a;
      }
    }
  }
  __syncthreads();

  // weighted sum: this block owns e-range [ch*1024, ch*1024+1024); 4 row-streams
  const float* ep = enc + (size_t)b * NL * NE + ch * 1024 + tid * 4;
  f32x4 a0 = {0.f, 0.f, 0.f, 0.f}, a1 = a0, a2 = a0, a3 = a0;
#pragma unroll 2
  for (int l = 0; l < NL; l += 4) {  // NL = 196 = 4*49
    f32x4 v0 = *reinterpret_cast<const f32x4*>(ep + (size_t)l * NE);
    f32x4 v1 = *reinterpret_cast<const f32x4*>(ep + (size_t)(l + 1) * NE);
    f32x4 v2 = *reinterpret_cast<const f32x4*>(ep + (size_t)(l + 2) * NE);
    f32x4 v3 = *reinterpret_cast<const f32x4*>(ep + (size_t)(l + 3) * NE);
    float c0 = al[l], c1 = al[l + 1], c2 = al[l + 2], c3 = al[l + 3];
#pragma unroll
    for (int j = 0; j < 4; ++j) {
      a0[j] = fmaf(c0, v0[j], a0[j]);
      a1[j] = fmaf(c1, v1[j], a1[j]);
      a2[j] = fmaf(c2, v2[j], a2[j]);
      a3[j] = fmaf(c3, v3[j], a3[j]);
    }
  }
  f32x4 s4;
#pragma unroll
  for (int j = 0; j < 4; ++j) s4[j] = (a0[j] + a1[j]) + (a2[j] + a3[j]);
  *reinterpret_cast<f32x4*>(awe + (size_t)b * NE + ch * 1024 + tid * 4) = s4;
}

extern "C" void kernel_launch(void* const* d_in, const int* in_sizes, int n_in,
                              void* d_out, int out_size, void* d_ws, size_t ws_size,
                              hipStream_t stream) {
  const float* enc  = (const float*)d_in[0];
  const float* dec  = (const float*)d_in[1];
  const float* Wenc = (const float*)d_in[2];
  const float* benc = (const float*)d_in[3];
  const float* Wdec = (const float*)d_in[4];
  const float* bdec = (const float*)d_in[5];
  const float* Watt = (const float*)d_in[6];
  const float* batt = (const float*)d_in[7];

  float* awe   = (float*)d_out;                     // [NB][NE]
  float* alpha = (float*)d_out + (size_t)NB * NE;   // [NB][NL]

  char* ws = (char*)d_ws;
  unsigned short* Bp = (unsigned short*)ws;                       // 2 MB
  float* d2  = (float*)(ws + (size_t)2 * 1024 * 1024);            // 512 KB
  float* att = (float*)(ws + (size_t)2 * 1024 * 1024 + 512 * 1024);  // 200 KB

  k_prep<<<dim3(288), dim3(512), 0, stream>>>(Wenc, Bp, dec, Wdec, bdec, benc, d2);
  k_main<<<dim3(NM / BM), dim3(512), 0, stream>>>(enc, Bp, d2, Watt, batt, att);
  k_awe<<<dim3(NB * 2), dim3(256), 0, stream>>>(enc, att, alpha, awe);
}